// Round 1
// baseline (825.841 us; speedup 1.0000x reference)
//
#include <hip/hip_runtime.h>
#include <hip/hip_bf16.h>

#define IN_FEATS  32
#define OUT_FEATS 64
#define GRIDSZ    8
#define KDIM      (IN_FEATS * GRIDSZ)   // 256 (i,k) pairs per trig branch
#define NPB       8                      // nodes per block in kernel A

// ---------------------------------------------------------------------------
// Kernel A: per-node messages  M[n][j] = sum_{i,k} cos(x[n][i]*(k+1))*C0[j][i][k]
//                                      + sin(x[n][i]*(k+1))*C1[j][i][k]
// block = 64 threads (one wave), thread = j, NPB nodes per block.
// cos/sin staged in LDS (read as wave-broadcast), coeffs as per-thread float4.
// ---------------------------------------------------------------------------
__global__ __launch_bounds__(64) void fkan_node_msg(
    const float* __restrict__ x,        // [N,32]
    const float* __restrict__ fc,       // [2,64,32,8]
    float* __restrict__ M,              // [N,64] out
    int n_nodes)
{
    __shared__ float cs[2][NPB][KDIM];  // 16 KB
    const int j = threadIdx.x;          // 0..63
    const int nbase = blockIdx.x * NPB;

    // Fill cos/sin table: NPB*KDIM = 2048 entries, 64 threads -> 32 each.
    for (int t = j; t < NPB * KDIM; t += 64) {
        const int node = t >> 8;        // t / KDIM
        const int ik   = t & (KDIM - 1);
        const int i    = ik >> 3;
        const int k    = ik & 7;
        const int n    = nbase + node;
        const float xv = (n < n_nodes) ? x[n * IN_FEATS + i] : 0.f;
        float s, c;
        __sincosf(xv * (float)(k + 1), &s, &c);
        cs[0][node][ik] = c;
        cs[1][node][ik] = s;
    }
    __syncthreads();

    const float4* c0 = (const float4*)(fc + (size_t)j * KDIM);
    const float4* c1 = (const float4*)(fc + (size_t)OUT_FEATS * KDIM + (size_t)j * KDIM);

    float acc[NPB];
#pragma unroll
    for (int u = 0; u < NPB; ++u) acc[u] = 0.f;

#pragma unroll 4
    for (int t4 = 0; t4 < KDIM / 4; ++t4) {
        const float4 a0 = c0[t4];
        const float4 a1 = c1[t4];
#pragma unroll
        for (int u = 0; u < NPB; ++u) {
            const float4 b0 = *(const float4*)&cs[0][u][t4 * 4];
            const float4 b1 = *(const float4*)&cs[1][u][t4 * 4];
            acc[u] += a0.x * b0.x + a0.y * b0.y + a0.z * b0.z + a0.w * b0.w
                    + a1.x * b1.x + a1.y * b1.y + a1.z * b1.z + a1.w * b1.w;
        }
    }

    const int rem = n_nodes - nbase;
#pragma unroll
    for (int u = 0; u < NPB; ++u) {
        if (u < rem) M[(size_t)(nbase + u) * OUT_FEATS + j] = acc[u];
    }
}

// ---------------------------------------------------------------------------
// Kernel B: out[n][j] = bias[j]
// ---------------------------------------------------------------------------
__global__ __launch_bounds__(256) void fkan_init_out(
    float* __restrict__ out, const float* __restrict__ bias, int total)
{
    const int t = blockIdx.x * 256 + threadIdx.x;
    if (t < total) out[t] = bias[t & (OUT_FEATS - 1)];
}

// ---------------------------------------------------------------------------
// Kernel C: scatter  out[dst[e]] += M[src[e]]   (16 threads/edge, float4 each)
// ---------------------------------------------------------------------------
__global__ __launch_bounds__(256) void fkan_scatter(
    const int* __restrict__ src,
    const int* __restrict__ dst,
    const float* __restrict__ M,
    float* __restrict__ out,
    int n_edges)
{
    const int tid = blockIdx.x * 256 + threadIdx.x;
    const int e = tid >> 4;
    const int q = tid & 15;
    if (e >= n_edges) return;
    const int s = src[e];
    const int d = dst[e];
    const float4 v = *(const float4*)(M + (size_t)s * OUT_FEATS + q * 4);
    float* o = out + (size_t)d * OUT_FEATS + q * 4;
    atomicAdd(o + 0, v.x);
    atomicAdd(o + 1, v.y);
    atomicAdd(o + 2, v.z);
    atomicAdd(o + 3, v.w);
}

// ---------------------------------------------------------------------------
extern "C" void kernel_launch(void* const* d_in, const int* in_sizes, int n_in,
                              void* d_out, int out_size, void* d_ws, size_t ws_size,
                              hipStream_t stream)
{
    const float* x    = (const float*)d_in[0];   // [N,32]
    const int*   src  = (const int*)d_in[1];     // [E]
    const int*   dst  = (const int*)d_in[2];     // [E]
    const float* fc   = (const float*)d_in[3];   // [2,64,32,8]
    const float* bias = (const float*)d_in[4];   // [64]
    float* out = (float*)d_out;                  // [N,64]

    const int n_nodes = in_sizes[0] / IN_FEATS;
    const int n_edges = in_sizes[1];

    float* M = (float*)d_ws;                     // [N,64] scratch (12.8 MB)

    // A: per-node messages
    {
        const int blocks = (n_nodes + NPB - 1) / NPB;
        fkan_node_msg<<<blocks, 64, 0, stream>>>(x, fc, M, n_nodes);
    }
    // B: init out with bias
    {
        const int total = n_nodes * OUT_FEATS;
        fkan_init_out<<<(total + 255) / 256, 256, 0, stream>>>(out, bias, total);
    }
    // C: scatter-add along edges
    {
        const long long threads = (long long)n_edges * 16;
        const int blocks = (int)((threads + 255) / 256);
        fkan_scatter<<<blocks, 256, 0, stream>>>(src, dst, M, out, n_edges);
    }
}

// Round 2
// 370.807 us; speedup vs baseline: 2.2271x; 2.2271x over previous
//
#include <hip/hip_runtime.h>
#include <hip/hip_bf16.h>

#define IN_FEATS  32
#define OUT_FEATS 64
#define GRIDSZ    8
#define KDIM      (IN_FEATS * GRIDSZ)   // 256 (i,k) pairs per trig branch
#define NPB       8                      // nodes per block in kernel A

// ---------------------------------------------------------------------------
// Kernel A: per-node messages  M[n][j] = sum_{i,k} cos(x[n][i]*(k+1))*C0[j][i][k]
//                                      + sin(x[n][i]*(k+1))*C1[j][i][k]
// block = 64 threads (one wave), thread = j, NPB nodes per block.
// M stored as bf16 (halves gather traffic; error ~0.002 rel, well in budget).
// ---------------------------------------------------------------------------
__global__ __launch_bounds__(64) void fkan_node_msg(
    const float* __restrict__ x,        // [N,32]
    const float* __restrict__ fc,       // [2,64,32,8]
    __hip_bfloat16* __restrict__ M,     // [N,64] out (bf16)
    int n_nodes)
{
    __shared__ float cs[2][NPB][KDIM];  // 16 KB
    const int j = threadIdx.x;          // 0..63
    const int nbase = blockIdx.x * NPB;

    for (int t = j; t < NPB * KDIM; t += 64) {
        const int node = t >> 8;
        const int ik   = t & (KDIM - 1);
        const int i    = ik >> 3;
        const int k    = ik & 7;
        const int n    = nbase + node;
        const float xv = (n < n_nodes) ? x[n * IN_FEATS + i] : 0.f;
        float s, c;
        __sincosf(xv * (float)(k + 1), &s, &c);
        cs[0][node][ik] = c;
        cs[1][node][ik] = s;
    }
    __syncthreads();

    const float4* c0 = (const float4*)(fc + (size_t)j * KDIM);
    const float4* c1 = (const float4*)(fc + (size_t)OUT_FEATS * KDIM + (size_t)j * KDIM);

    float acc[NPB];
#pragma unroll
    for (int u = 0; u < NPB; ++u) acc[u] = 0.f;

#pragma unroll 4
    for (int t4 = 0; t4 < KDIM / 4; ++t4) {
        const float4 a0 = c0[t4];
        const float4 a1 = c1[t4];
#pragma unroll
        for (int u = 0; u < NPB; ++u) {
            const float4 b0 = *(const float4*)&cs[0][u][t4 * 4];
            const float4 b1 = *(const float4*)&cs[1][u][t4 * 4];
            acc[u] += a0.x * b0.x + a0.y * b0.y + a0.z * b0.z + a0.w * b0.w
                    + a1.x * b1.x + a1.y * b1.y + a1.z * b1.z + a1.w * b1.w;
        }
    }

    const int rem = n_nodes - nbase;
#pragma unroll
    for (int u = 0; u < NPB; ++u) {
        if (u < rem) M[(size_t)(nbase + u) * OUT_FEATS + j] = __float2bfloat16(acc[u]);
    }
}

// ---------------------------------------------------------------------------
// CSR build: zero counts -> histogram(dst) -> exclusive scan -> bucket fill
// ---------------------------------------------------------------------------
__global__ __launch_bounds__(256) void fkan_zero(int* __restrict__ p, int n)
{
    const int t = blockIdx.x * 256 + threadIdx.x;
    if (t < n) p[t] = 0;
}

__global__ __launch_bounds__(256) void fkan_hist(
    const int* __restrict__ dst, int* __restrict__ counts, int n_edges)
{
    const int e = blockIdx.x * 256 + threadIdx.x;
    if (e < n_edges) atomicAdd(&counts[dst[e]], 1);
}

// single block, 1024 threads: exclusive scan of counts[0..n) -> offs, cursor
__global__ __launch_bounds__(1024) void fkan_scan(
    const int* __restrict__ counts, int* __restrict__ offs,
    int* __restrict__ cursor, int n_nodes)
{
    __shared__ int part[1024];
    const int t = threadIdx.x;
    const int chunk = (n_nodes + 1023) / 1024;
    const int lo = min(t * chunk, n_nodes);
    const int hi = min(lo + chunk, n_nodes);
    int s = 0;
    for (int i = lo; i < hi; ++i) s += counts[i];
    part[t] = s;
    __syncthreads();
    // inclusive scan (Hillis-Steele)
    for (int d = 1; d < 1024; d <<= 1) {
        const int v = (t >= d) ? part[t - d] : 0;
        __syncthreads();
        part[t] += v;
        __syncthreads();
    }
    int run = (t == 0) ? 0 : part[t - 1];
    for (int i = lo; i < hi; ++i) {
        offs[i] = run;
        cursor[i] = run;
        run += counts[i];
    }
    if (t == 1023) offs[n_nodes] = part[1023];
}

__global__ __launch_bounds__(256) void fkan_bucket(
    const int* __restrict__ src, const int* __restrict__ dst,
    int* __restrict__ cursor, int* __restrict__ ebuf, int n_edges)
{
    const int e = blockIdx.x * 256 + threadIdx.x;
    if (e < n_edges) {
        const int pos = atomicAdd(&cursor[dst[e]], 1);
        ebuf[pos] = src[e];
    }
}

// ---------------------------------------------------------------------------
// Gather: one wave per dst node; lane = output feature j.
// out[n][j] = bias[j] + sum_{e in CSR[n]} M[ebuf[e]][j]
// ---------------------------------------------------------------------------
__global__ __launch_bounds__(256) void fkan_gather(
    const int* __restrict__ offs, const int* __restrict__ ebuf,
    const __hip_bfloat16* __restrict__ M, const float* __restrict__ bias,
    float* __restrict__ out, int n_nodes)
{
    const int lane = threadIdx.x & 63;
    const int node = blockIdx.x * 4 + (threadIdx.x >> 6);
    if (node >= n_nodes) return;
    const int beg = offs[node];
    const int end = offs[node + 1];
    float acc = 0.f;
    int e = beg;
    for (; e + 4 <= end; e += 4) {
        const int s0 = ebuf[e + 0];
        const int s1 = ebuf[e + 1];
        const int s2 = ebuf[e + 2];
        const int s3 = ebuf[e + 3];
        const float v0 = __bfloat162float(M[(size_t)s0 * OUT_FEATS + lane]);
        const float v1 = __bfloat162float(M[(size_t)s1 * OUT_FEATS + lane]);
        const float v2 = __bfloat162float(M[(size_t)s2 * OUT_FEATS + lane]);
        const float v3 = __bfloat162float(M[(size_t)s3 * OUT_FEATS + lane]);
        acc += (v0 + v1) + (v2 + v3);
    }
    for (; e < end; ++e)
        acc += __bfloat162float(M[(size_t)ebuf[e] * OUT_FEATS + lane]);
    out[(size_t)node * OUT_FEATS + lane] = acc + bias[lane];
}

// ---------------------------------------------------------------------------
extern "C" void kernel_launch(void* const* d_in, const int* in_sizes, int n_in,
                              void* d_out, int out_size, void* d_ws, size_t ws_size,
                              hipStream_t stream)
{
    const float* x    = (const float*)d_in[0];   // [N,32]
    const int*   src  = (const int*)d_in[1];     // [E]
    const int*   dst  = (const int*)d_in[2];     // [E]
    const float* fc   = (const float*)d_in[3];   // [2,64,32,8]
    const float* bias = (const float*)d_in[4];   // [64]
    float* out = (float*)d_out;                  // [N,64]

    const int n_nodes = in_sizes[0] / IN_FEATS;
    const int n_edges = in_sizes[1];

    // workspace layout (~10.2 MB total)
    char* ws = (char*)d_ws;
    __hip_bfloat16* M = (__hip_bfloat16*)ws;              // N*64*2 B
    int* offs   = (int*)(ws + (size_t)n_nodes * OUT_FEATS * 2);
    int* cursor = offs + (n_nodes + 1);
    int* counts = cursor + n_nodes;
    int* ebuf   = counts + n_nodes;                       // E ints

    // A: per-node messages (bf16)
    fkan_node_msg<<<(n_nodes + NPB - 1) / NPB, 64, 0, stream>>>(x, fc, M, n_nodes);

    // CSR build
    fkan_zero<<<(n_nodes + 255) / 256, 256, 0, stream>>>(counts, n_nodes);
    fkan_hist<<<(n_edges + 255) / 256, 256, 0, stream>>>(dst, counts, n_edges);
    fkan_scan<<<1, 1024, 0, stream>>>(counts, offs, cursor, n_nodes);
    fkan_bucket<<<(n_edges + 255) / 256, 256, 0, stream>>>(src, dst, cursor, ebuf, n_edges);

    // Gather + bias
    fkan_gather<<<(n_nodes + 3) / 4, 256, 0, stream>>>(offs, ebuf, M, bias, out, n_nodes);
}

// Round 3
// 254.520 us; speedup vs baseline: 3.2447x; 1.4569x over previous
//
#include <hip/hip_runtime.h>
#include <hip/hip_bf16.h>

#define IN_FEATS  32
#define OUT_FEATS 64
#define GRIDSZ    8
#define KDIM      512                    // 2 branches * 32 i * 8 k
#define NPB       64                     // nodes per block in kernel A

typedef __attribute__((ext_vector_type(8))) short bf16x8;
typedef __attribute__((ext_vector_type(4))) float f32x4;

static __device__ __forceinline__ unsigned short f2bf(float f) {
    unsigned u = __builtin_bit_cast(unsigned, f);
    return (unsigned short)((u + 0x7fffu + ((u >> 16) & 1u)) >> 16);   // RNE
}
static __device__ __forceinline__ float bf2f(unsigned short h) {
    return __builtin_bit_cast(float, (unsigned)h << 16);
}

// ---------------------------------------------------------------------------
// W prep: fc [2][64][32*8] fp32  ->  Wb [64][512] bf16, K = branch*256 + i*8 + k
// ---------------------------------------------------------------------------
__global__ __launch_bounds__(256) void fkan_wprep(
    const float* __restrict__ fc, unsigned short* __restrict__ Wb)
{
    const int t = blockIdx.x * 256 + threadIdx.x;
    if (t >= 2 * OUT_FEATS * 256) return;
    const int j  = t >> 9;
    const int r  = t & 511;
    const int b  = r >> 8;
    const int ik = r & 255;
    Wb[t] = f2bf(fc[(b * OUT_FEATS + j) * 256 + ik]);
}

// ---------------------------------------------------------------------------
// Kernel A (MFMA): M[n][j] = sum_K Phi[n][K] * Wb[j][K]
// Phi[n][K]: K<256 -> cos((k+1)*x[n][i]), K>=256 -> sin, built via Chebyshev
// recurrence. LDS rows XOR-swizzled (byte ^= (row&7)<<4) for conflict-free
// ds_read_b128 A-fragments. 256 thr = 4 waves, wave = 16-wide j-tile.
// ---------------------------------------------------------------------------
__global__ __launch_bounds__(256) void fkan_node_msg(
    const float* __restrict__ x,             // [N,32]
    const unsigned short* __restrict__ Wb,   // [64][512] bf16
    unsigned short* __restrict__ M,          // [N,64] bf16 out
    int n_nodes)
{
    __shared__ __align__(16) short phi[NPB * KDIM];  // 64 KB
    const int tid  = threadIdx.x;
    const int lane = tid & 63;
    const int wid  = tid >> 6;                 // 0..3 -> j-tile
    const int nbase = blockIdx.x * NPB;

    // ---- preload B fragments for this wave's 16 j's (16 k-steps, 64 VGPR) ----
    const int j0   = wid * 16;
    const int brow = j0 + (lane & 15);
    const int kofs = 8 * (lane >> 4);
    bf16x8 bfrag[16];
#pragma unroll
    for (int ks = 0; ks < 16; ++ks)
        bfrag[ks] = *(const bf16x8*)(Wb + brow * KDIM + ks * 32 + kofs);

    // ---- build Phi: thread -> (node = tid>>2, 8 consecutive i) ----
    {
        const int node = tid >> 2;
        const int q    = tid & 3;
        const int n    = nbase + node;
        char* rowp = (char*)phi + node * 1024;
        const int sw = (node & 7) << 4;
        float xv[8];
        if (n < n_nodes) {
            const float4 a = *(const float4*)(x + (size_t)n * 32 + q * 8);
            const float4 b = *(const float4*)(x + (size_t)n * 32 + q * 8 + 4);
            xv[0]=a.x; xv[1]=a.y; xv[2]=a.z; xv[3]=a.w;
            xv[4]=b.x; xv[5]=b.y; xv[6]=b.z; xv[7]=b.w;
        } else {
#pragma unroll
            for (int u = 0; u < 8; ++u) xv[u] = 0.f;
        }
#pragma unroll
        for (int u = 0; u < 8; ++u) {
            const int i = q * 8 + u;
            float s1, c1;
            __sincosf(xv[u], &s1, &c1);
            const float twoc = 2.f * c1;
            float cAm = 1.f, sAm = 0.f, cA = c1, sA = s1;
#pragma unroll
            for (int p = 0; p < 4; ++p) {
                const float cB = twoc * cA - cAm;   // c_{2p+2}
                const float sB = twoc * sA - sAm;   // s_{2p+2}
                const unsigned pc = ((unsigned)f2bf(cB) << 16) | f2bf(cA);
                const unsigned ps = ((unsigned)f2bf(sB) << 16) | f2bf(sA);
                const int Kc = i * 8 + 2 * p;
                *(unsigned*)(rowp + ((Kc * 2) ^ sw))         = pc;
                *(unsigned*)(rowp + (((256 + Kc) * 2) ^ sw)) = ps;
                const float cN = twoc * cB - cA;    // c_{2p+3}
                const float sN = twoc * sB - sA;
                cAm = cB; sAm = sB; cA = cN; sA = sN;
            }
        }
    }
    __syncthreads();

    // ---- MFMA: 4 node-subtiles x 16 k-steps ----
    f32x4 acc[4] = {{0.f,0.f,0.f,0.f},{0.f,0.f,0.f,0.f},
                    {0.f,0.f,0.f,0.f},{0.f,0.f,0.f,0.f}};
    const int arow = lane & 15;
    const int sw   = (arow & 7) << 4;          // nt*16 doesn't change row&7
    const int kbyt = 16 * (lane >> 4);
#pragma unroll
    for (int ks = 0; ks < 16; ++ks) {
#pragma unroll
        for (int nt = 0; nt < 4; ++nt) {
            const int row = nt * 16 + arow;
            const bf16x8 afrag = *(const bf16x8*)
                ((const char*)phi + row * 1024 + ((ks * 64 + kbyt) ^ sw));
            acc[nt] = __builtin_amdgcn_mfma_f32_16x16x32_bf16(
                afrag, bfrag[ks], acc[nt], 0, 0, 0);
        }
    }

    // ---- store: D row = (lane>>4)*4 + r (node), col = lane&15 (j) ----
    const int rem = n_nodes - nbase;
#pragma unroll
    for (int nt = 0; nt < 4; ++nt) {
        const int rbase = nt * 16 + (lane >> 4) * 4;
#pragma unroll
        for (int r = 0; r < 4; ++r) {
            const int node = rbase + r;
            if (node < rem)
                M[(size_t)(nbase + node) * OUT_FEATS + j0 + (lane & 15)] =
                    f2bf(acc[nt][r]);
        }
    }
}

// ---------------------------------------------------------------------------
// CSR build: zero -> histogram(dst) -> single-block scan -> bucket fill
// ---------------------------------------------------------------------------
__global__ __launch_bounds__(256) void fkan_zero(int* __restrict__ p, int n)
{
    const int t = blockIdx.x * 256 + threadIdx.x;
    if (t < n) p[t] = 0;
}

__global__ __launch_bounds__(256) void fkan_hist(
    const int* __restrict__ dst, int* __restrict__ counts, int n_edges)
{
    const int e = blockIdx.x * 256 + threadIdx.x;
    if (e < n_edges) atomicAdd(&counts[dst[e]], 1);
}

__global__ __launch_bounds__(1024) void fkan_scan(
    const int* __restrict__ counts, int* __restrict__ offs,
    int* __restrict__ cursor, int n_nodes)
{
    __shared__ int part[1024];
    const int t = threadIdx.x;
    const int chunk = (n_nodes + 1023) / 1024;
    const int lo = min(t * chunk, n_nodes);
    const int hi = min(lo + chunk, n_nodes);
    int s = 0;
    for (int i = lo; i < hi; ++i) s += counts[i];
    part[t] = s;
    __syncthreads();
    for (int d = 1; d < 1024; d <<= 1) {
        const int v = (t >= d) ? part[t - d] : 0;
        __syncthreads();
        part[t] += v;
        __syncthreads();
    }
    int run = (t == 0) ? 0 : part[t - 1];
    for (int i = lo; i < hi; ++i) {
        offs[i] = run;
        cursor[i] = run;
        run += counts[i];
    }
    if (t == 1023) offs[n_nodes] = part[1023];
}

__global__ __launch_bounds__(256) void fkan_bucket(
    const int* __restrict__ src, const int* __restrict__ dst,
    int* __restrict__ cursor, int* __restrict__ ebuf, int n_edges)
{
    const int e = blockIdx.x * 256 + threadIdx.x;
    if (e < n_edges) {
        const int pos = atomicAdd(&cursor[dst[e]], 1);
        ebuf[pos] = src[e];
    }
}

// ---------------------------------------------------------------------------
// Gather: wave per dst node; 4 edges per iteration (lane-quarter = edge slot,
// lane&15 = 4-col group, ushort4 loads), shfl-xor reduce, float4 store.
// ---------------------------------------------------------------------------
__global__ __launch_bounds__(256) void fkan_gather(
    const int* __restrict__ offs, const int* __restrict__ ebuf,
    const unsigned short* __restrict__ M, const float* __restrict__ bias,
    float* __restrict__ out, int n_nodes)
{
    const int lane = threadIdx.x & 63;
    const int node = blockIdx.x * 4 + (threadIdx.x >> 6);
    if (node >= n_nodes) return;
    const int beg = offs[node], end = offs[node + 1];
    const int sub = lane >> 4;
    const int col = (lane & 15) * 4;
    float ax = 0.f, ay = 0.f, az = 0.f, aw = 0.f;
    for (int e = beg; e < end; e += 4) {
        const int ee = e + sub;
        if (ee < end) {
            const int s = ebuf[ee];
            const ushort4 v = *(const ushort4*)(M + (size_t)s * OUT_FEATS + col);
            ax += bf2f(v.x); ay += bf2f(v.y); az += bf2f(v.z); aw += bf2f(v.w);
        }
    }
#pragma unroll
    for (int mask = 16; mask <= 32; mask <<= 1) {
        ax += __shfl_xor(ax, mask);
        ay += __shfl_xor(ay, mask);
        az += __shfl_xor(az, mask);
        aw += __shfl_xor(aw, mask);
    }
    if (sub == 0) {
        const float4 b = *(const float4*)(bias + col);
        float4 o; o.x = ax + b.x; o.y = ay + b.y; o.z = az + b.z; o.w = aw + b.w;
        *(float4*)(out + (size_t)node * OUT_FEATS + col) = o;
    }
}

// ---------------------------------------------------------------------------
extern "C" void kernel_launch(void* const* d_in, const int* in_sizes, int n_in,
                              void* d_out, int out_size, void* d_ws, size_t ws_size,
                              hipStream_t stream)
{
    const float* x    = (const float*)d_in[0];   // [N,32]
    const int*   src  = (const int*)d_in[1];     // [E]
    const int*   dst  = (const int*)d_in[2];     // [E]
    const float* fc   = (const float*)d_in[3];   // [2,64,32,8]
    const float* bias = (const float*)d_in[4];   // [64]
    float* out = (float*)d_out;                  // [N,64]

    const int n_nodes = in_sizes[0] / IN_FEATS;
    const int n_edges = in_sizes[1];

    // workspace layout
    char* ws = (char*)d_ws;
    unsigned short* M  = (unsigned short*)ws;                       // N*64*2 B
    unsigned short* Wb = (unsigned short*)(ws + (size_t)n_nodes * OUT_FEATS * 2);
    int* offs   = (int*)((char*)Wb + 2 * OUT_FEATS * 256 * 2);
    int* cursor = offs + (n_nodes + 1);
    int* counts = cursor + n_nodes;
    int* ebuf   = counts + n_nodes;                                 // E ints

    // W -> bf16
    fkan_wprep<<<(2 * OUT_FEATS * 256 + 255) / 256, 256, 0, stream>>>(fc, Wb);

    // A: per-node messages via MFMA
    fkan_node_msg<<<(n_nodes + NPB - 1) / NPB, 256, 0, stream>>>(x, Wb, M, n_nodes);

    // CSR build
    fkan_zero<<<(n_nodes + 255) / 256, 256, 0, stream>>>(counts, n_nodes);
    fkan_hist<<<(n_edges + 255) / 256, 256, 0, stream>>>(dst, counts, n_edges);
    fkan_scan<<<1, 1024, 0, stream>>>(counts, offs, cursor, n_nodes);
    fkan_bucket<<<(n_edges + 255) / 256, 256, 0, stream>>>(src, dst, cursor, ebuf, n_edges);

    // Gather + bias
    fkan_gather<<<(n_nodes + 3) / 4, 256, 0, stream>>>(offs, ebuf, M, bias, out, n_nodes);
}

// Round 4
// 155.695 us; speedup vs baseline: 5.3042x; 1.6347x over previous
//
#include <hip/hip_runtime.h>
#include <hip/hip_bf16.h>

#define IN_FEATS  32
#define OUT_FEATS 64
#define GRIDSZ    8
#define KDIM      512                    // 2 branches * 32 i * 8 k
#define NPB       64                     // nodes per block in kernel A

typedef __attribute__((ext_vector_type(8))) short bf16x8;
typedef __attribute__((ext_vector_type(4))) float f32x4;

static __device__ __forceinline__ unsigned short f2bf(float f) {
    unsigned u = __builtin_bit_cast(unsigned, f);
    return (unsigned short)((u + 0x7fffu + ((u >> 16) & 1u)) >> 16);   // RNE
}
static __device__ __forceinline__ float bf2f(unsigned short h) {
    return __builtin_bit_cast(float, (unsigned)h << 16);
}

// ---------------------------------------------------------------------------
// W prep: fc [2][64][32*8] fp32  ->  Wb [64][512] bf16, K = branch*256 + i*8 + k
// ---------------------------------------------------------------------------
__global__ __launch_bounds__(256) void fkan_wprep(
    const float* __restrict__ fc, unsigned short* __restrict__ Wb)
{
    const int t = blockIdx.x * 256 + threadIdx.x;
    if (t >= 2 * OUT_FEATS * 256) return;
    const int j  = t >> 9;
    const int r  = t & 511;
    const int b  = r >> 8;
    const int ik = r & 255;
    Wb[t] = f2bf(fc[(b * OUT_FEATS + j) * 256 + ik]);
}

// ---------------------------------------------------------------------------
// Kernel A (MFMA): M[n][j] = sum_K Phi[n][K] * Wb[j][K]
// Phi built via Chebyshev recurrence; LDS XOR-swizzled for ds_read_b128.
// ---------------------------------------------------------------------------
__global__ __launch_bounds__(256) void fkan_node_msg(
    const float* __restrict__ x,             // [N,32]
    const unsigned short* __restrict__ Wb,   // [64][512] bf16
    unsigned short* __restrict__ M,          // [N,64] bf16 out
    int n_nodes)
{
    __shared__ __align__(16) short phi[NPB * KDIM];  // 64 KB
    const int tid  = threadIdx.x;
    const int lane = tid & 63;
    const int wid  = tid >> 6;                 // 0..3 -> j-tile
    const int nbase = blockIdx.x * NPB;

    const int j0   = wid * 16;
    const int brow = j0 + (lane & 15);
    const int kofs = 8 * (lane >> 4);
    bf16x8 bfrag[16];
#pragma unroll
    for (int ks = 0; ks < 16; ++ks)
        bfrag[ks] = *(const bf16x8*)(Wb + brow * KDIM + ks * 32 + kofs);

    {
        const int node = tid >> 2;
        const int q    = tid & 3;
        const int n    = nbase + node;
        char* rowp = (char*)phi + node * 1024;
        const int sw = (node & 7) << 4;
        float xv[8];
        if (n < n_nodes) {
            const float4 a = *(const float4*)(x + (size_t)n * 32 + q * 8);
            const float4 b = *(const float4*)(x + (size_t)n * 32 + q * 8 + 4);
            xv[0]=a.x; xv[1]=a.y; xv[2]=a.z; xv[3]=a.w;
            xv[4]=b.x; xv[5]=b.y; xv[6]=b.z; xv[7]=b.w;
        } else {
#pragma unroll
            for (int u = 0; u < 8; ++u) xv[u] = 0.f;
        }
#pragma unroll
        for (int u = 0; u < 8; ++u) {
            const int i = q * 8 + u;
            float s1, c1;
            __sincosf(xv[u], &s1, &c1);
            const float twoc = 2.f * c1;
            float cAm = 1.f, sAm = 0.f, cA = c1, sA = s1;
#pragma unroll
            for (int p = 0; p < 4; ++p) {
                const float cB = twoc * cA - cAm;
                const float sB = twoc * sA - sAm;
                const unsigned pc = ((unsigned)f2bf(cB) << 16) | f2bf(cA);
                const unsigned ps = ((unsigned)f2bf(sB) << 16) | f2bf(sA);
                const int Kc = i * 8 + 2 * p;
                *(unsigned*)(rowp + ((Kc * 2) ^ sw))         = pc;
                *(unsigned*)(rowp + (((256 + Kc) * 2) ^ sw)) = ps;
                const float cN = twoc * cB - cA;
                const float sN = twoc * sB - sA;
                cAm = cB; sAm = sB; cA = cN; sA = sN;
            }
        }
    }
    __syncthreads();

    f32x4 acc[4] = {{0.f,0.f,0.f,0.f},{0.f,0.f,0.f,0.f},
                    {0.f,0.f,0.f,0.f},{0.f,0.f,0.f,0.f}};
    const int arow = lane & 15;
    const int sw   = (arow & 7) << 4;
    const int kbyt = 16 * (lane >> 4);
#pragma unroll
    for (int ks = 0; ks < 16; ++ks) {
#pragma unroll
        for (int nt = 0; nt < 4; ++nt) {
            const int row = nt * 16 + arow;
            const bf16x8 afrag = *(const bf16x8*)
                ((const char*)phi + row * 1024 + ((ks * 64 + kbyt) ^ sw));
            acc[nt] = __builtin_amdgcn_mfma_f32_16x16x32_bf16(
                afrag, bfrag[ks], acc[nt], 0, 0, 0);
        }
    }

    const int rem = n_nodes - nbase;
#pragma unroll
    for (int nt = 0; nt < 4; ++nt) {
        const int rbase = nt * 16 + (lane >> 4) * 4;
#pragma unroll
        for (int r = 0; r < 4; ++r) {
            const int node = rbase + r;
            if (node < rem)
                M[(size_t)(nbase + node) * OUT_FEATS + j0 + (lane & 15)] =
                    f2bf(acc[nt][r]);
        }
    }
}

// ---------------------------------------------------------------------------
// CSR build: zero -> histogram(dst) -> 3-pass scan -> bucket fill
// ---------------------------------------------------------------------------
__global__ __launch_bounds__(256) void fkan_zero(int* __restrict__ p, int n)
{
    const int t = blockIdx.x * 256 + threadIdx.x;
    if (t < n) p[t] = 0;
}

__global__ __launch_bounds__(256) void fkan_hist(
    const int* __restrict__ dst, int* __restrict__ counts, int n_edges)
{
    const int e = blockIdx.x * 256 + threadIdx.x;
    if (e < n_edges) atomicAdd(&counts[dst[e]], 1);
}

// pass 1: per-block (256-wide) sums of counts -> bsum
__global__ __launch_bounds__(256) void fkan_scan1(
    const int* __restrict__ counts, int* __restrict__ bsum, int n_nodes)
{
    const int gid = blockIdx.x * 256 + threadIdx.x;
    int v = (gid < n_nodes) ? counts[gid] : 0;
#pragma unroll
    for (int m = 1; m < 64; m <<= 1) v += __shfl_xor(v, m);
    __shared__ int wsum[4];
    if ((threadIdx.x & 63) == 0) wsum[threadIdx.x >> 6] = v;
    __syncthreads();
    if (threadIdx.x == 0)
        bsum[blockIdx.x] = wsum[0] + wsum[1] + wsum[2] + wsum[3];
}

// pass 2: one block scans the (<=1024) block sums -> exclusive boff;
// also writes offs[n_nodes] = n_edges (known total).
__global__ __launch_bounds__(1024) void fkan_scan2(
    const int* __restrict__ bsum, int* __restrict__ boff,
    int* __restrict__ offs_last, int nblk, int n_edges)
{
    __shared__ int part[1024];
    const int t = threadIdx.x;
    part[t] = (t < nblk) ? bsum[t] : 0;
    __syncthreads();
    for (int d = 1; d < 1024; d <<= 1) {
        const int v = (t >= d) ? part[t - d] : 0;
        __syncthreads();
        part[t] += v;
        __syncthreads();
    }
    if (t < nblk) boff[t] = (t == 0) ? 0 : part[t - 1];
    if (t == 0) offs_last[0] = n_edges;
}

// pass 3: block-local exclusive scan + block offset -> offs, cursor
__global__ __launch_bounds__(256) void fkan_scan3(
    const int* __restrict__ counts, const int* __restrict__ boff,
    int* __restrict__ offs, int* __restrict__ cursor, int n_nodes)
{
    __shared__ int part[256];
    const int t = threadIdx.x;
    const int gid = blockIdx.x * 256 + t;
    const int c = (gid < n_nodes) ? counts[gid] : 0;
    part[t] = c;
    __syncthreads();
    for (int d = 1; d < 256; d <<= 1) {
        const int v = (t >= d) ? part[t - d] : 0;
        __syncthreads();
        part[t] += v;
        __syncthreads();
    }
    if (gid < n_nodes) {
        const int ex = boff[blockIdx.x] + part[t] - c;
        offs[gid] = ex;
        cursor[gid] = ex;
    }
}

__global__ __launch_bounds__(256) void fkan_bucket(
    const int* __restrict__ src, const int* __restrict__ dst,
    int* __restrict__ cursor, int* __restrict__ ebuf, int n_edges)
{
    const int e = blockIdx.x * 256 + threadIdx.x;
    if (e < n_edges) {
        const int pos = atomicAdd(&cursor[dst[e]], 1);
        ebuf[pos] = src[e];
    }
}

// ---------------------------------------------------------------------------
// Gather: wave per dst node; 4 edges/iter, ushort4 per lane, shfl-xor reduce.
// ---------------------------------------------------------------------------
__global__ __launch_bounds__(256) void fkan_gather(
    const int* __restrict__ offs, const int* __restrict__ ebuf,
    const unsigned short* __restrict__ M, const float* __restrict__ bias,
    float* __restrict__ out, int n_nodes)
{
    const int lane = threadIdx.x & 63;
    const int node = blockIdx.x * 4 + (threadIdx.x >> 6);
    if (node >= n_nodes) return;
    const int beg = offs[node], end = offs[node + 1];
    const int sub = lane >> 4;
    const int col = (lane & 15) * 4;
    float ax = 0.f, ay = 0.f, az = 0.f, aw = 0.f;
    for (int e = beg; e < end; e += 4) {
        const int ee = e + sub;
        if (ee < end) {
            const int s = ebuf[ee];
            const ushort4 v = *(const ushort4*)(M + (size_t)s * OUT_FEATS + col);
            ax += bf2f(v.x); ay += bf2f(v.y); az += bf2f(v.z); aw += bf2f(v.w);
        }
    }
#pragma unroll
    for (int mask = 16; mask <= 32; mask <<= 1) {
        ax += __shfl_xor(ax, mask);
        ay += __shfl_xor(ay, mask);
        az += __shfl_xor(az, mask);
        aw += __shfl_xor(aw, mask);
    }
    if (sub == 0) {
        const float4 b = *(const float4*)(bias + col);
        float4 o; o.x = ax + b.x; o.y = ay + b.y; o.z = az + b.z; o.w = aw + b.w;
        *(float4*)(out + (size_t)node * OUT_FEATS + col) = o;
    }
}

// ---------------------------------------------------------------------------
extern "C" void kernel_launch(void* const* d_in, const int* in_sizes, int n_in,
                              void* d_out, int out_size, void* d_ws, size_t ws_size,
                              hipStream_t stream)
{
    const float* x    = (const float*)d_in[0];   // [N,32]
    const int*   src  = (const int*)d_in[1];     // [E]
    const int*   dst  = (const int*)d_in[2];     // [E]
    const float* fc   = (const float*)d_in[3];   // [2,64,32,8]
    const float* bias = (const float*)d_in[4];   // [64]
    float* out = (float*)d_out;                  // [N,64]

    const int n_nodes = in_sizes[0] / IN_FEATS;
    const int n_edges = in_sizes[1];
    const int nblk    = (n_nodes + 255) / 256;   // scan blocks (<=1024)

    // workspace layout
    char* ws = (char*)d_ws;
    unsigned short* M  = (unsigned short*)ws;                       // N*64*2 B
    unsigned short* Wb = (unsigned short*)(ws + (size_t)n_nodes * OUT_FEATS * 2);
    int* offs   = (int*)((char*)Wb + 2 * OUT_FEATS * 256 * 2);
    int* cursor = offs + (n_nodes + 1);
    int* counts = cursor + n_nodes;
    int* bsum   = counts + n_nodes;
    int* boff   = bsum + nblk;
    int* ebuf   = boff + nblk;                                      // E ints

    // W -> bf16
    fkan_wprep<<<(2 * OUT_FEATS * 256 + 255) / 256, 256, 0, stream>>>(fc, Wb);

    // A: per-node messages via MFMA
    fkan_node_msg<<<(n_nodes + NPB - 1) / NPB, 256, 0, stream>>>(x, Wb, M, n_nodes);

    // CSR build
    fkan_zero<<<(n_nodes + 255) / 256, 256, 0, stream>>>(counts, n_nodes);
    fkan_hist<<<(n_edges + 255) / 256, 256, 0, stream>>>(dst, counts, n_edges);
    fkan_scan1<<<nblk, 256, 0, stream>>>(counts, bsum, n_nodes);
    fkan_scan2<<<1, 1024, 0, stream>>>(bsum, boff, offs + n_nodes, nblk, n_edges);
    fkan_scan3<<<nblk, 256, 0, stream>>>(counts, boff, offs, cursor, n_nodes);
    fkan_bucket<<<(n_edges + 255) / 256, 256, 0, stream>>>(src, dst, cursor, ebuf, n_edges);

    // Gather + bias
    fkan_gather<<<(n_nodes + 3) / 4, 256, 0, stream>>>(offs, ebuf, M, bias, out, n_nodes);
}

// Round 5
// 144.794 us; speedup vs baseline: 5.7035x; 1.0753x over previous
//
#include <hip/hip_runtime.h>
#include <hip/hip_bf16.h>

#define IN_FEATS  32
#define OUT_FEATS 64
#define GRIDSZ    8
#define KDIM      512                    // 2 branches * 32 i * 8 k
#define NPB       64                     // nodes per block in kernel A

typedef __attribute__((ext_vector_type(8))) short bf16x8;
typedef __attribute__((ext_vector_type(4))) float f32x4;

static __device__ __forceinline__ unsigned short f2bf(float f) {
    unsigned u = __builtin_bit_cast(unsigned, f);
    return (unsigned short)((u + 0x7fffu + ((u >> 16) & 1u)) >> 16);   // RNE
}
static __device__ __forceinline__ float bf2f(unsigned short h) {
    return __builtin_bit_cast(float, (unsigned)h << 16);
}

// ---------------------------------------------------------------------------
// W prep: fc [2][64][32*8] fp32  ->  Wb [64][512] bf16, K = branch*256 + i*8 + k
// ---------------------------------------------------------------------------
__global__ __launch_bounds__(256) void fkan_wprep(
    const float* __restrict__ fc, unsigned short* __restrict__ Wb)
{
    const int t = blockIdx.x * 256 + threadIdx.x;
    if (t >= 2 * OUT_FEATS * 256) return;
    const int j  = t >> 9;
    const int r  = t & 511;
    const int b  = r >> 8;
    const int ik = r & 255;
    Wb[t] = f2bf(fc[(b * OUT_FEATS + j) * 256 + ik]);
}

// ---------------------------------------------------------------------------
// Kernel A (MFMA): M[n][j] = sum_K Phi[n][K] * Wb[j][K]
// Phi built via Chebyshev recurrence; LDS XOR-swizzled for ds_read_b128.
// ---------------------------------------------------------------------------
__global__ __launch_bounds__(256) void fkan_node_msg(
    const float* __restrict__ x,             // [N,32]
    const unsigned short* __restrict__ Wb,   // [64][512] bf16
    unsigned short* __restrict__ M,          // [N,64] bf16 out
    int n_nodes)
{
    __shared__ __align__(16) short phi[NPB * KDIM];  // 64 KB
    const int tid  = threadIdx.x;
    const int lane = tid & 63;
    const int wid  = tid >> 6;                 // 0..3 -> j-tile
    const int nbase = blockIdx.x * NPB;

    const int j0   = wid * 16;
    const int brow = j0 + (lane & 15);
    const int kofs = 8 * (lane >> 4);
    bf16x8 bfrag[16];
#pragma unroll
    for (int ks = 0; ks < 16; ++ks)
        bfrag[ks] = *(const bf16x8*)(Wb + brow * KDIM + ks * 32 + kofs);

    {
        const int node = tid >> 2;
        const int q    = tid & 3;
        const int n    = nbase + node;
        char* rowp = (char*)phi + node * 1024;
        const int sw = (node & 7) << 4;
        float xv[8];
        if (n < n_nodes) {
            const float4 a = *(const float4*)(x + (size_t)n * 32 + q * 8);
            const float4 b = *(const float4*)(x + (size_t)n * 32 + q * 8 + 4);
            xv[0]=a.x; xv[1]=a.y; xv[2]=a.z; xv[3]=a.w;
            xv[4]=b.x; xv[5]=b.y; xv[6]=b.z; xv[7]=b.w;
        } else {
#pragma unroll
            for (int u = 0; u < 8; ++u) xv[u] = 0.f;
        }
#pragma unroll
        for (int u = 0; u < 8; ++u) {
            const int i = q * 8 + u;
            float s1, c1;
            __sincosf(xv[u], &s1, &c1);
            const float twoc = 2.f * c1;
            float cAm = 1.f, sAm = 0.f, cA = c1, sA = s1;
#pragma unroll
            for (int p = 0; p < 4; ++p) {
                const float cB = twoc * cA - cAm;
                const float sB = twoc * sA - sAm;
                const unsigned pc = ((unsigned)f2bf(cB) << 16) | f2bf(cA);
                const unsigned ps = ((unsigned)f2bf(sB) << 16) | f2bf(sA);
                const int Kc = i * 8 + 2 * p;
                *(unsigned*)(rowp + ((Kc * 2) ^ sw))         = pc;
                *(unsigned*)(rowp + (((256 + Kc) * 2) ^ sw)) = ps;
                const float cN = twoc * cB - cA;
                const float sN = twoc * sB - sA;
                cAm = cB; sAm = sB; cA = cN; sA = sN;
            }
        }
    }
    __syncthreads();

    f32x4 acc[4] = {{0.f,0.f,0.f,0.f},{0.f,0.f,0.f,0.f},
                    {0.f,0.f,0.f,0.f},{0.f,0.f,0.f,0.f}};
    const int arow = lane & 15;
    const int sw   = (arow & 7) << 4;
    const int kbyt = 16 * (lane >> 4);
#pragma unroll
    for (int ks = 0; ks < 16; ++ks) {
#pragma unroll
        for (int nt = 0; nt < 4; ++nt) {
            const int row = nt * 16 + arow;
            const bf16x8 afrag = *(const bf16x8*)
                ((const char*)phi + row * 1024 + ((ks * 64 + kbyt) ^ sw));
            acc[nt] = __builtin_amdgcn_mfma_f32_16x16x32_bf16(
                afrag, bfrag[ks], acc[nt], 0, 0, 0);
        }
    }

    const int rem = n_nodes - nbase;
#pragma unroll
    for (int nt = 0; nt < 4; ++nt) {
        const int rbase = nt * 16 + (lane >> 4) * 4;
#pragma unroll
        for (int r = 0; r < 4; ++r) {
            const int node = rbase + r;
            if (node < rem)
                M[(size_t)(nbase + node) * OUT_FEATS + j0 + (lane & 15)] =
                    f2bf(acc[nt][r]);
        }
    }
}

// ---------------------------------------------------------------------------
// CSR build: zero -> histogram(dst) -> 3-pass scan -> XCD-filtered bucket fill
// ---------------------------------------------------------------------------
__global__ __launch_bounds__(256) void fkan_zero(int* __restrict__ p, int n)
{
    const int t = blockIdx.x * 256 + threadIdx.x;
    if (t < n) p[t] = 0;
}

__global__ __launch_bounds__(256) void fkan_hist(
    const int* __restrict__ dst, int* __restrict__ counts, int n_edges)
{
    const int e = blockIdx.x * 256 + threadIdx.x;
    if (e < n_edges) atomicAdd(&counts[dst[e]], 1);
}

// pass 1: per-block (256-wide) sums of counts -> bsum
__global__ __launch_bounds__(256) void fkan_scan1(
    const int* __restrict__ counts, int* __restrict__ bsum, int n_nodes)
{
    const int gid = blockIdx.x * 256 + threadIdx.x;
    int v = (gid < n_nodes) ? counts[gid] : 0;
#pragma unroll
    for (int m = 1; m < 64; m <<= 1) v += __shfl_xor(v, m);
    __shared__ int wsum[4];
    if ((threadIdx.x & 63) == 0) wsum[threadIdx.x >> 6] = v;
    __syncthreads();
    if (threadIdx.x == 0)
        bsum[blockIdx.x] = wsum[0] + wsum[1] + wsum[2] + wsum[3];
}

// pass 2: one block scans the (<=1024) block sums -> exclusive boff;
// also writes offs[n_nodes] = n_edges (known total).
__global__ __launch_bounds__(1024) void fkan_scan2(
    const int* __restrict__ bsum, int* __restrict__ boff,
    int* __restrict__ offs_last, int nblk, int n_edges)
{
    __shared__ int part[1024];
    const int t = threadIdx.x;
    part[t] = (t < nblk) ? bsum[t] : 0;
    __syncthreads();
    for (int d = 1; d < 1024; d <<= 1) {
        const int v = (t >= d) ? part[t - d] : 0;
        __syncthreads();
        part[t] += v;
        __syncthreads();
    }
    if (t < nblk) boff[t] = (t == 0) ? 0 : part[t - 1];
    if (t == 0) offs_last[0] = n_edges;
}

// pass 3: block-local exclusive scan + block offset -> offs, cursor
__global__ __launch_bounds__(256) void fkan_scan3(
    const int* __restrict__ counts, const int* __restrict__ boff,
    int* __restrict__ offs, int* __restrict__ cursor, int n_nodes)
{
    __shared__ int part[256];
    const int t = threadIdx.x;
    const int gid = blockIdx.x * 256 + t;
    const int c = (gid < n_nodes) ? counts[gid] : 0;
    part[t] = c;
    __syncthreads();
    for (int d = 1; d < 256; d <<= 1) {
        const int v = (t >= d) ? part[t - d] : 0;
        __syncthreads();
        part[t] += v;
        __syncthreads();
    }
    if (gid < n_nodes) {
        const int ex = boff[blockIdx.x] + part[t] - c;
        offs[gid] = ex;
        cursor[gid] = ex;
    }
}

// Bucket fill, XCD-range-filtered: block b (XCD ~ b&7) handles edge slab b>>3
// but only edges with dst in node-range (b&7). All writes to a given ebuf
// region then issue from one XCD -> lines coalesce in its L2 (no ping-pong).
__global__ __launch_bounds__(256) void fkan_bucket(
    const int* __restrict__ src, const int* __restrict__ dst,
    int* __restrict__ cursor, int* __restrict__ ebuf,
    int n_edges, int n8)
{
    const int r    = blockIdx.x & 7;
    const int slab = blockIdx.x >> 3;
    const int e    = slab * 256 + threadIdx.x;
    if (e >= n_edges) return;
    const int d = dst[e];
    if ((unsigned)(d - r * n8) < (unsigned)n8) {
        const int pos = atomicAdd(&cursor[d], 1);
        ebuf[pos] = src[e];
    }
}

// ---------------------------------------------------------------------------
// Gather: wave per dst node; 4 edges/iter, ushort4 per lane, shfl-xor reduce.
// ---------------------------------------------------------------------------
__global__ __launch_bounds__(256) void fkan_gather(
    const int* __restrict__ offs, const int* __restrict__ ebuf,
    const unsigned short* __restrict__ M, const float* __restrict__ bias,
    float* __restrict__ out, int n_nodes)
{
    const int lane = threadIdx.x & 63;
    const int node = blockIdx.x * 4 + (threadIdx.x >> 6);
    if (node >= n_nodes) return;
    const int beg = offs[node], end = offs[node + 1];
    const int sub = lane >> 4;
    const int col = (lane & 15) * 4;
    float ax = 0.f, ay = 0.f, az = 0.f, aw = 0.f;
    for (int e = beg; e < end; e += 4) {
        const int ee = e + sub;
        if (ee < end) {
            const int s = ebuf[ee];
            const ushort4 v = *(const ushort4*)(M + (size_t)s * OUT_FEATS + col);
            ax += bf2f(v.x); ay += bf2f(v.y); az += bf2f(v.z); aw += bf2f(v.w);
        }
    }
#pragma unroll
    for (int mask = 16; mask <= 32; mask <<= 1) {
        ax += __shfl_xor(ax, mask);
        ay += __shfl_xor(ay, mask);
        az += __shfl_xor(az, mask);
        aw += __shfl_xor(aw, mask);
    }
    if (sub == 0) {
        const float4 b = *(const float4*)(bias + col);
        float4 o; o.x = ax + b.x; o.y = ay + b.y; o.z = az + b.z; o.w = aw + b.w;
        *(float4*)(out + (size_t)node * OUT_FEATS + col) = o;
    }
}

// ---------------------------------------------------------------------------
extern "C" void kernel_launch(void* const* d_in, const int* in_sizes, int n_in,
                              void* d_out, int out_size, void* d_ws, size_t ws_size,
                              hipStream_t stream)
{
    const float* x    = (const float*)d_in[0];   // [N,32]
    const int*   src  = (const int*)d_in[1];     // [E]
    const int*   dst  = (const int*)d_in[2];     // [E]
    const float* fc   = (const float*)d_in[3];   // [2,64,32,8]
    const float* bias = (const float*)d_in[4];   // [64]
    float* out = (float*)d_out;                  // [N,64]

    const int n_nodes = in_sizes[0] / IN_FEATS;
    const int n_edges = in_sizes[1];
    const int nblk    = (n_nodes + 255) / 256;   // scan blocks (<=1024)
    const int n8      = (n_nodes + 7) / 8;       // nodes per XCD range

    // workspace layout
    char* ws = (char*)d_ws;
    unsigned short* M  = (unsigned short*)ws;                       // N*64*2 B
    unsigned short* Wb = (unsigned short*)(ws + (size_t)n_nodes * OUT_FEATS * 2);
    int* offs   = (int*)((char*)Wb + 2 * OUT_FEATS * 256 * 2);
    int* cursor = offs + (n_nodes + 1);
    int* counts = cursor + n_nodes;
    int* bsum   = counts + n_nodes;
    int* boff   = bsum + nblk;
    int* ebuf   = boff + nblk;                                      // E ints

    // W -> bf16
    fkan_wprep<<<(2 * OUT_FEATS * 256 + 255) / 256, 256, 0, stream>>>(fc, Wb);

    // A: per-node messages via MFMA
    fkan_node_msg<<<(n_nodes + NPB - 1) / NPB, 256, 0, stream>>>(x, Wb, M, n_nodes);

    // CSR build
    fkan_zero<<<(n_nodes + 255) / 256, 256, 0, stream>>>(counts, n_nodes);
    fkan_hist<<<(n_edges + 255) / 256, 256, 0, stream>>>(dst, counts, n_edges);
    fkan_scan1<<<nblk, 256, 0, stream>>>(counts, bsum, n_nodes);
    fkan_scan2<<<1, 1024, 0, stream>>>(bsum, boff, offs + n_nodes, nblk, n_edges);
    fkan_scan3<<<nblk, 256, 0, stream>>>(counts, boff, offs, cursor, n_nodes);
    fkan_bucket<<<8 * ((n_edges + 255) / 256), 256, 0, stream>>>(
        src, dst, cursor, ebuf, n_edges, n8);

    // Gather + bias
    fkan_gather<<<(n_nodes + 3) / 4, 256, 0, stream>>>(offs, ebuf, M, bias, out, n_nodes);
}

// Round 6
// 137.491 us; speedup vs baseline: 6.0065x; 1.0531x over previous
//
#include <hip/hip_runtime.h>
#include <hip/hip_bf16.h>

#define IN_FEATS  32
#define OUT_FEATS 64
#define GRIDSZ    8
#define KDIM      512                    // 2 branches * 32 i * 8 k
#define NPB       64                     // nodes per block in kernel A

typedef __attribute__((ext_vector_type(8))) short bf16x8;
typedef __attribute__((ext_vector_type(4))) float f32x4;

static __device__ __forceinline__ unsigned short f2bf(float f) {
    unsigned u = __builtin_bit_cast(unsigned, f);
    return (unsigned short)((u + 0x7fffu + ((u >> 16) & 1u)) >> 16);   // RNE
}
static __device__ __forceinline__ float bf2f(unsigned short h) {
    return __builtin_bit_cast(float, (unsigned)h << 16);
}

// ---------------------------------------------------------------------------
// Kernel A (MFMA): M[n][j] = sum_K Phi[n][K] * W[j][K]
// W fragments converted fp32->bf16 in-register from fc (no wprep kernel).
// Phi built via Chebyshev recurrence; LDS XOR-swizzled for ds_read_b128.
// Also zeroes counts[] (disjoint buffer, consumed later by hist).
// ---------------------------------------------------------------------------
__global__ __launch_bounds__(256) void fkan_node_msg(
    const float* __restrict__ x,             // [N,32]
    const float* __restrict__ fc,            // [2,64,32,8] fp32
    unsigned short* __restrict__ M,          // [N,64] bf16 out
    int* __restrict__ counts,                // [N] zeroed here
    int n_nodes)
{
    __shared__ __align__(16) short phi[NPB * KDIM];  // 64 KB
    const int tid  = threadIdx.x;
    const int lane = tid & 63;
    const int wid  = tid >> 6;                 // 0..3 -> j-tile
    const int nbase = blockIdx.x * NPB;

    // fused zero of counts: block covers NPB node slots
    if (tid < NPB) {
        const int n = nbase + tid;
        if (n < n_nodes) counts[n] = 0;
    }

    // ---- B fragments direct from fc: K = b*256 + i*8 + k ----
    const int j0   = wid * 16;
    const int brow = j0 + (lane & 15);
    const int kofs = 8 * (lane >> 4);
    bf16x8 bfrag[16];
#pragma unroll
    for (int ks = 0; ks < 16; ++ks) {
        const int K  = ks * 32 + kofs;        // 8 consecutive K, same (b,i)
        const int b  = K >> 8;
        const int ik = K & 255;
        const float* p = fc + ((size_t)(b * OUT_FEATS + brow) * 256 + ik);
        const float4 f0 = *(const float4*)p;
        const float4 f1 = *(const float4*)(p + 4);
        bf16x8 t;
        t[0] = (short)f2bf(f0.x); t[1] = (short)f2bf(f0.y);
        t[2] = (short)f2bf(f0.z); t[3] = (short)f2bf(f0.w);
        t[4] = (short)f2bf(f1.x); t[5] = (short)f2bf(f1.y);
        t[6] = (short)f2bf(f1.z); t[7] = (short)f2bf(f1.w);
        bfrag[ks] = t;
    }

    // ---- build Phi ----
    {
        const int node = tid >> 2;
        const int q    = tid & 3;
        const int n    = nbase + node;
        char* rowp = (char*)phi + node * 1024;
        const int sw = (node & 7) << 4;
        float xv[8];
        if (n < n_nodes) {
            const float4 a = *(const float4*)(x + (size_t)n * 32 + q * 8);
            const float4 b = *(const float4*)(x + (size_t)n * 32 + q * 8 + 4);
            xv[0]=a.x; xv[1]=a.y; xv[2]=a.z; xv[3]=a.w;
            xv[4]=b.x; xv[5]=b.y; xv[6]=b.z; xv[7]=b.w;
        } else {
#pragma unroll
            for (int u = 0; u < 8; ++u) xv[u] = 0.f;
        }
#pragma unroll
        for (int u = 0; u < 8; ++u) {
            const int i = q * 8 + u;
            float s1, c1;
            __sincosf(xv[u], &s1, &c1);
            const float twoc = 2.f * c1;
            float cAm = 1.f, sAm = 0.f, cA = c1, sA = s1;
#pragma unroll
            for (int p = 0; p < 4; ++p) {
                const float cB = twoc * cA - cAm;
                const float sB = twoc * sA - sAm;
                const unsigned pc = ((unsigned)f2bf(cB) << 16) | f2bf(cA);
                const unsigned ps = ((unsigned)f2bf(sB) << 16) | f2bf(sA);
                const int Kc = i * 8 + 2 * p;
                *(unsigned*)(rowp + ((Kc * 2) ^ sw))         = pc;
                *(unsigned*)(rowp + (((256 + Kc) * 2) ^ sw)) = ps;
                const float cN = twoc * cB - cA;
                const float sN = twoc * sB - sA;
                cAm = cB; sAm = sB; cA = cN; sA = sN;
            }
        }
    }
    __syncthreads();

    f32x4 acc[4] = {{0.f,0.f,0.f,0.f},{0.f,0.f,0.f,0.f},
                    {0.f,0.f,0.f,0.f},{0.f,0.f,0.f,0.f}};
    const int arow = lane & 15;
    const int sw   = (arow & 7) << 4;
    const int kbyt = 16 * (lane >> 4);
#pragma unroll
    for (int ks = 0; ks < 16; ++ks) {
#pragma unroll
        for (int nt = 0; nt < 4; ++nt) {
            const int row = nt * 16 + arow;
            const bf16x8 afrag = *(const bf16x8*)
                ((const char*)phi + row * 1024 + ((ks * 64 + kbyt) ^ sw));
            acc[nt] = __builtin_amdgcn_mfma_f32_16x16x32_bf16(
                afrag, bfrag[ks], acc[nt], 0, 0, 0);
        }
    }

    const int rem = n_nodes - nbase;
#pragma unroll
    for (int nt = 0; nt < 4; ++nt) {
        const int rbase = nt * 16 + (lane >> 4) * 4;
#pragma unroll
        for (int r = 0; r < 4; ++r) {
            const int node = rbase + r;
            if (node < rem)
                M[(size_t)(nbase + node) * OUT_FEATS + j0 + (lane & 15)] =
                    f2bf(acc[nt][r]);
        }
    }
}

// ---------------------------------------------------------------------------
// CSR build: histogram(dst) -> 3-pass scan -> XCD-filtered bucket fill
// ---------------------------------------------------------------------------
__global__ __launch_bounds__(256) void fkan_hist(
    const int* __restrict__ dst, int* __restrict__ counts, int n_edges)
{
    const int e0 = (blockIdx.x * 256 + threadIdx.x) * 4;
    if (e0 + 3 < n_edges) {
        const int4 d4 = *(const int4*)(dst + e0);
        atomicAdd(&counts[d4.x], 1);
        atomicAdd(&counts[d4.y], 1);
        atomicAdd(&counts[d4.z], 1);
        atomicAdd(&counts[d4.w], 1);
    } else {
        for (int e = e0; e < n_edges; ++e) atomicAdd(&counts[dst[e]], 1);
    }
}

// pass 1: per-block (256-wide) sums of counts -> bsum
__global__ __launch_bounds__(256) void fkan_scan1(
    const int* __restrict__ counts, int* __restrict__ bsum, int n_nodes)
{
    const int gid = blockIdx.x * 256 + threadIdx.x;
    int v = (gid < n_nodes) ? counts[gid] : 0;
#pragma unroll
    for (int m = 1; m < 64; m <<= 1) v += __shfl_xor(v, m);
    __shared__ int wsum[4];
    if ((threadIdx.x & 63) == 0) wsum[threadIdx.x >> 6] = v;
    __syncthreads();
    if (threadIdx.x == 0)
        bsum[blockIdx.x] = wsum[0] + wsum[1] + wsum[2] + wsum[3];
}

// pass 2: one block scans the (<=1024) block sums -> exclusive boff;
// also writes offs[n_nodes] = n_edges.
__global__ __launch_bounds__(1024) void fkan_scan2(
    const int* __restrict__ bsum, int* __restrict__ boff,
    int* __restrict__ offs_last, int nblk, int n_edges)
{
    __shared__ int part[1024];
    const int t = threadIdx.x;
    part[t] = (t < nblk) ? bsum[t] : 0;
    __syncthreads();
    for (int d = 1; d < 1024; d <<= 1) {
        const int v = (t >= d) ? part[t - d] : 0;
        __syncthreads();
        part[t] += v;
        __syncthreads();
    }
    if (t < nblk) boff[t] = (t == 0) ? 0 : part[t - 1];
    if (t == 0) offs_last[0] = n_edges;
}

// pass 3: block-local exclusive scan + block offset -> offs, cursor
__global__ __launch_bounds__(256) void fkan_scan3(
    const int* __restrict__ counts, const int* __restrict__ boff,
    int* __restrict__ offs, int* __restrict__ cursor, int n_nodes)
{
    __shared__ int part[256];
    const int t = threadIdx.x;
    const int gid = blockIdx.x * 256 + t;
    const int c = (gid < n_nodes) ? counts[gid] : 0;
    part[t] = c;
    __syncthreads();
    for (int d = 1; d < 256; d <<= 1) {
        const int v = (t >= d) ? part[t - d] : 0;
        __syncthreads();
        part[t] += v;
        __syncthreads();
    }
    if (gid < n_nodes) {
        const int ex = boff[blockIdx.x] + part[t] - c;
        offs[gid] = ex;
        cursor[gid] = ex;
    }
}

// Bucket fill, XCD-range-filtered, int4 reads, ushort payload (src < 65536).
__global__ __launch_bounds__(256) void fkan_bucket(
    const int* __restrict__ src, const int* __restrict__ dst,
    int* __restrict__ cursor, unsigned short* __restrict__ ebuf,
    int n_edges, int n8)
{
    const int r    = blockIdx.x & 7;
    const int slab = blockIdx.x >> 3;
    const int e0   = (slab * 256 + threadIdx.x) * 4;
    if (e0 >= n_edges) return;
    const int lim = r * n8;
    if (e0 + 3 < n_edges) {
        const int4 d4 = *(const int4*)(dst + e0);
        const int4 s4 = *(const int4*)(src + e0);
        if ((unsigned)(d4.x - lim) < (unsigned)n8)
            ebuf[atomicAdd(&cursor[d4.x], 1)] = (unsigned short)s4.x;
        if ((unsigned)(d4.y - lim) < (unsigned)n8)
            ebuf[atomicAdd(&cursor[d4.y], 1)] = (unsigned short)s4.y;
        if ((unsigned)(d4.z - lim) < (unsigned)n8)
            ebuf[atomicAdd(&cursor[d4.z], 1)] = (unsigned short)s4.z;
        if ((unsigned)(d4.w - lim) < (unsigned)n8)
            ebuf[atomicAdd(&cursor[d4.w], 1)] = (unsigned short)s4.w;
    } else {
        for (int e = e0; e < n_edges; ++e) {
            const int d = dst[e];
            if ((unsigned)(d - lim) < (unsigned)n8)
                ebuf[atomicAdd(&cursor[d], 1)] = (unsigned short)src[e];
        }
    }
}

// ---------------------------------------------------------------------------
// Gather: wave per dst node; 8 edges in flight (8 lanes x 16B per edge row),
// 3-round shfl-xor reduce, float4 stores.
// ---------------------------------------------------------------------------
__global__ __launch_bounds__(256) void fkan_gather(
    const int* __restrict__ offs, const unsigned short* __restrict__ ebuf,
    const unsigned short* __restrict__ M, const float* __restrict__ bias,
    float* __restrict__ out, int n_nodes)
{
    const int lane = threadIdx.x & 63;
    const int node = blockIdx.x * 4 + (threadIdx.x >> 6);
    if (node >= n_nodes) return;
    const int beg = offs[node], end = offs[node + 1];
    const int sub  = lane >> 3;        // 0..7 edge slot
    const int colb = (lane & 7) * 8;   // 8-col group
    float a0=0.f,a1=0.f,a2=0.f,a3=0.f,a4=0.f,a5=0.f,a6=0.f,a7=0.f;
    for (int e = beg; e < end; e += 8) {
        const int ee = e + sub;
        if (ee < end) {
            const int s = ebuf[ee];
            const bf16x8 v = *(const bf16x8*)(M + (size_t)s * OUT_FEATS + colb);
            a0 += bf2f((unsigned short)v[0]); a1 += bf2f((unsigned short)v[1]);
            a2 += bf2f((unsigned short)v[2]); a3 += bf2f((unsigned short)v[3]);
            a4 += bf2f((unsigned short)v[4]); a5 += bf2f((unsigned short)v[5]);
            a6 += bf2f((unsigned short)v[6]); a7 += bf2f((unsigned short)v[7]);
        }
    }
#pragma unroll
    for (int m = 8; m <= 32; m <<= 1) {
        a0 += __shfl_xor(a0, m); a1 += __shfl_xor(a1, m);
        a2 += __shfl_xor(a2, m); a3 += __shfl_xor(a3, m);
        a4 += __shfl_xor(a4, m); a5 += __shfl_xor(a5, m);
        a6 += __shfl_xor(a6, m); a7 += __shfl_xor(a7, m);
    }
    if (sub == 0) {
        const float4 b0 = *(const float4*)(bias + colb);
        const float4 b1 = *(const float4*)(bias + colb + 4);
        float4 o0; o0.x = a0 + b0.x; o0.y = a1 + b0.y; o0.z = a2 + b0.z; o0.w = a3 + b0.w;
        float4 o1; o1.x = a4 + b1.x; o1.y = a5 + b1.y; o1.z = a6 + b1.z; o1.w = a7 + b1.w;
        *(float4*)(out + (size_t)node * OUT_FEATS + colb)     = o0;
        *(float4*)(out + (size_t)node * OUT_FEATS + colb + 4) = o1;
    }
}

// ---------------------------------------------------------------------------
extern "C" void kernel_launch(void* const* d_in, const int* in_sizes, int n_in,
                              void* d_out, int out_size, void* d_ws, size_t ws_size,
                              hipStream_t stream)
{
    const float* x    = (const float*)d_in[0];   // [N,32]
    const int*   src  = (const int*)d_in[1];     // [E]
    const int*   dst  = (const int*)d_in[2];     // [E]
    const float* fc   = (const float*)d_in[3];   // [2,64,32,8]
    const float* bias = (const float*)d_in[4];   // [64]
    float* out = (float*)d_out;                  // [N,64]

    const int n_nodes = in_sizes[0] / IN_FEATS;
    const int n_edges = in_sizes[1];
    const int nblk    = (n_nodes + 255) / 256;   // scan blocks (<=1024)
    const int n8      = (n_nodes + 7) / 8;       // nodes per XCD range

    // workspace layout
    char* ws = (char*)d_ws;
    unsigned short* M = (unsigned short*)ws;                        // N*64*2 B
    int* offs   = (int*)(ws + (size_t)n_nodes * OUT_FEATS * 2);
    int* cursor = offs + (n_nodes + 1);
    int* counts = cursor + n_nodes;
    int* bsum   = counts + n_nodes;
    int* boff   = bsum + nblk;
    unsigned short* ebuf = (unsigned short*)(boff + nblk);          // E ushort

    // A: per-node messages via MFMA (also zeroes counts)
    fkan_node_msg<<<(n_nodes + NPB - 1) / NPB, 256, 0, stream>>>(
        x, fc, M, counts, n_nodes);

    // CSR build
    fkan_hist<<<(n_edges + 1023) / 1024, 256, 0, stream>>>(dst, counts, n_edges);
    fkan_scan1<<<nblk, 256, 0, stream>>>(counts, bsum, n_nodes);
    fkan_scan2<<<1, 1024, 0, stream>>>(bsum, boff, offs + n_nodes, nblk, n_edges);
    fkan_scan3<<<nblk, 256, 0, stream>>>(counts, boff, offs, cursor, n_nodes);
    fkan_bucket<<<8 * ((n_edges + 1023) / 1024), 256, 0, stream>>>(
        src, dst, cursor, ebuf, n_edges, n8);

    // Gather + bias
    fkan_gather<<<(n_nodes + 3) / 4, 256, 0, stream>>>(offs, ebuf, M, bias, out, n_nodes);
}